// Round 4
// baseline (992.211 us; speedup 1.0000x reference)
//
#include <hip/hip_runtime.h>

// ---------------- problem constants ----------------
#define C_CH   512
#define HFEAT  50
#define WFEAT  50
#define NROIS  256
#define D1     25088   // C_CH * 49
#define H1     4096
#define NHEAD  105     // 21 + 84

typedef __attribute__((ext_vector_type(8))) short short8;
typedef __attribute__((ext_vector_type(4))) float f32x4;

__device__ __forceinline__ unsigned short f2bf(float f) {
  unsigned int u = __float_as_uint(f);
  return (unsigned short)((u + 0x7fffu + ((u >> 16) & 1u)) >> 16);
}

__device__ __forceinline__ unsigned long long pack4(float4 v) {
  return (unsigned long long)f2bf(v.x)
       | ((unsigned long long)f2bf(v.y) << 16)
       | ((unsigned long long)f2bf(v.z) << 32)
       | ((unsigned long long)f2bf(v.w) << 48);
}

// ---------------- ROI max-pool (adaptive 7x7), fp32 -> bf16 ----------------
// grid (NROIS, 4) x 128 threads: 1024 blocks for TLP; thread = one channel.
__global__ __launch_bounds__(128)
void roi_pool_kernel(const float* __restrict__ feat, const float* __restrict__ boxes,
                     unsigned short* __restrict__ pooled) {
  const int roi = blockIdx.x;
  const int c   = blockIdx.y * 128 + threadIdx.x;
  const int bx1 = (int)(boxes[roi * 4 + 0] * 0.0625f);
  const int by1 = (int)(boxes[roi * 4 + 1] * 0.0625f);
  const int bx2 = (int)(boxes[roi * 4 + 2] * 0.0625f);
  const int by2 = (int)(boxes[roi * 4 + 3] * 0.0625f);

  const int rlo = min(max(by1, 0), HFEAT - 1);
  const int rhi = min(by2, HFEAT - 1);
  const int rn  = max(rhi - rlo + 1, 1);
  const int clo = min(max(bx1, 0), WFEAT - 1);
  const int chi = min(bx2, WFEAT - 1);
  const int cn  = max(chi - clo + 1, 1);

  const float* f = feat + (size_t)c * (HFEAT * WFEAT);
  unsigned short* op = pooled + (size_t)roi * D1 + c * 49;
  for (int i = 0; i < 7; ++i) {
    const int r0 = rlo + (i * rn) / 7;
    const int r1 = rlo + ((i + 1) * rn + 6) / 7;
    for (int j = 0; j < 7; ++j) {
      const int c0 = clo + (j * cn) / 7;
      const int c1 = clo + ((j + 1) * cn + 6) / 7;
      float m = -3.402823466e+38f;
      for (int y = r0; y < r1; ++y)
        for (int x = c0; x < c1; ++x)
          m = fmaxf(m, f[y * WFEAT + x]);
      op[i * 7 + j] = f2bf(m);
    }
  }
}

// ---------------- m256 split-K MFMA GEMM ----------------
// Tile 256(m = all of M) x 32(n) x 32(k); 256 threads = 4 waves, wave w owns
// rows [64w, 64w+64). Every B (weight) row is fetched from HBM exactly ONCE
// (128 B fp32 per MFMA); the A tile (12.8 MB total) is L2-resident since all
// n-blocks share it. A staged via global_load_lds (16B); B loaded coalesced
// (8 lanes x 16B = full 128B row chunk), converted bf16, padded LDS.
template <bool MASK_N>
__global__ __launch_bounds__(256, 4)
void gemm_m256(const unsigned short* __restrict__ A,  // [256,K] bf16 bits
               const float* __restrict__ B,           // [n_valid,K] fp32
               float* __restrict__ part,              // [S,256,Nt]
               const int Nt, const int K, const int kps, const int n_valid) {
  __shared__ __align__(16) unsigned short As[256 * 32];  // 16 KB
  __shared__ __align__(16) unsigned short Bs[32 * 40];   // 2.5 KB (pad +8)

  const int bn = blockIdx.x * 32;
  const int z  = blockIdx.y;
  const int k0 = z * kps;

  const int tid  = threadIdx.x;
  const int wave = tid >> 6;
  const int lane = tid & 63;
  const int lr   = lane & 15;
  const int kq   = lane >> 4;
  const int wm   = wave * 64;

  // A staging: 16 chunks of 16 rows; wave w stages chunks 4w..4w+3
  const unsigned short* ag[4];
#pragma unroll
  for (int i = 0; i < 4; ++i) {
    const int chunk = wave * 4 + i;
    ag[i] = A + (size_t)(chunk * 16 + (lane >> 2)) * K + k0 + (lane & 3) * 8;
  }
  // B staging: 8 threads/row (16B each), 32 rows
  const int brow = tid >> 3;
  const int bcol = (tid & 7) * 4;
  int browc = bn + brow;
  if (MASK_N) browc = min(browc, n_valid - 1);
  const float* bg = B + (size_t)browc * K + k0 + bcol;
  unsigned long long* bdst = (unsigned long long*)(Bs + brow * 40 + bcol);

  f32x4 acc[4][2];
#pragma unroll
  for (int im = 0; im < 4; ++im)
#pragma unroll
    for (int in = 0; in < 2; ++in)
      acc[im][in] = (f32x4){0.f, 0.f, 0.f, 0.f};

  const int iters = kps >> 5;
  for (int it = 0; it < iters; ++it) {
    __syncthreads();
    // ---- stage A (256x32 bf16 = 16 KB): 4 global_load_lds per wave ----
#pragma unroll
    for (int i = 0; i < 4; ++i) {
      __builtin_amdgcn_global_load_lds(
          (const __attribute__((address_space(1))) void*)ag[i],
          (__attribute__((address_space(3))) void*)(As + (wave * 4 + i) * 512),
          16, 0, 0);
      ag[i] += 32;
    }
    // ---- stage B (32x32 fp32 -> bf16), coalesced 128B row chunks ----
    const float4 v = *(const float4*)bg;
    bg += 32;
    *bdst = pack4(v);
    __syncthreads();
    // ---- fragments + 8 MFMAs per wave ----
    short8 af[4], bfr[2];
#pragma unroll
    for (int im = 0; im < 4; ++im)
      af[im] = *(const short8*)(As + (wm + im * 16 + lr) * 32 + kq * 8);
#pragma unroll
    for (int in = 0; in < 2; ++in)
      bfr[in] = *(const short8*)(Bs + (in * 16 + lr) * 40 + kq * 8);
#pragma unroll
    for (int im = 0; im < 4; ++im)
#pragma unroll
      for (int in = 0; in < 2; ++in)
        acc[im][in] = __builtin_amdgcn_mfma_f32_16x16x32_bf16(af[im], bfr[in], acc[im][in], 0, 0, 0);
  }

  // ---- write fp32 partials: C/D layout col=lane&15 (n), row=kq*4+r (m) ----
#pragma unroll
  for (int im = 0; im < 4; ++im) {
#pragma unroll
    for (int in = 0; in < 2; ++in) {
      const int m0 = wm + im * 16 + kq * 4;
      const int n  = bn + in * 16 + lr;
      float* p = part + ((size_t)z * NROIS + m0) * Nt + n;
#pragma unroll
      for (int r = 0; r < 4; ++r)
        p[(size_t)r * Nt] = acc[im][in][r];
    }
  }
}

// ---------------- split-K reduce + bias + relu + cast to bf16 ----------------
__global__ __launch_bounds__(256)
void reduce_bias_relu(const float* __restrict__ part, const float* __restrict__ bias,
                      unsigned short* __restrict__ out, const int MN, const int nmask,
                      const int S) {
  const int idx = (blockIdx.x * 256 + threadIdx.x) * 4;
  if (idx >= MN) return;
  float4 v = *(const float4*)(part + idx);
  for (int s = 1; s < S; ++s) {
    const float4 p = *(const float4*)(part + (size_t)s * MN + idx);
    v.x += p.x; v.y += p.y; v.z += p.z; v.w += p.w;
  }
  const float4 b = *(const float4*)(bias + (idx & nmask));
  v.x = fmaxf(v.x + b.x, 0.f);
  v.y = fmaxf(v.y + b.y, 0.f);
  v.z = fmaxf(v.z + b.z, 0.f);
  v.w = fmaxf(v.w + b.w, 0.f);
  unsigned long long o = (unsigned long long)f2bf(v.x)
                       | ((unsigned long long)f2bf(v.y) << 16)
                       | ((unsigned long long)f2bf(v.z) << 32)
                       | ((unsigned long long)f2bf(v.w) << 48);
  *(unsigned long long*)(out + idx) = o;
}

// ---------------- heads: reduce + bias, split into class/regr outputs ----------------
__global__ __launch_bounds__(128)
void heads_reduce(const float* __restrict__ part, const float* __restrict__ bc,
                  const float* __restrict__ br, float* __restrict__ out, const int S) {
  const int m = blockIdx.x;
  const int n = threadIdx.x;
  if (n >= NHEAD) return;
  float v = 0.f;
  for (int s = 0; s < S; ++s) v += part[((size_t)s * NROIS + m) * 128 + n];
  if (n < 21) out[m * 21 + n] = v + bc[n];
  else        out[NROIS * 21 + m * 84 + (n - 21)] = v + br[n - 21];
}

// ---------------- launch ----------------
extern "C" void kernel_launch(void* const* d_in, const int* in_sizes, int n_in,
                              void* d_out, int out_size, void* d_ws, size_t ws_size,
                              hipStream_t stream) {
  const float* feat  = (const float*)d_in[0];
  const float* boxes = (const float*)d_in[1];
  const float* W1    = (const float*)d_in[2];
  const float* b1    = (const float*)d_in[3];
  const float* W2    = (const float*)d_in[4];
  const float* b2    = (const float*)d_in[5];
  const float* Wc    = (const float*)d_in[6];
  const float* bc    = (const float*)d_in[7];
  const float* Wr    = (const float*)d_in[8];
  const float* br    = (const float*)d_in[9];
  float* out = (float*)d_out;

  // workspace layout (bytes)
  char* ws = (char*)d_ws;
  unsigned short* pooled = (unsigned short*)(ws);               // 12,845,056
  float*          part   = (float*)(ws + 12845056);             // 16*256*4096*4 = 67,108,864
  unsigned short* x1     = (unsigned short*)(ws + 79953920);    // 2,097,152
  unsigned short* x2     = (unsigned short*)(ws + 82051072);    // 2,097,152
  float*          Wh     = (float*)(ws + 84148224);             // 1,720,320
  float*          hpart  = (float*)(ws + 85868544);             // 16*256*128*4 = 2,097,152

  // concat Wc|Wr into one [105,4096] weight matrix
  hipMemcpyAsync(Wh, Wc, (size_t)21 * 4096 * 4, hipMemcpyDeviceToDevice, stream);
  hipMemcpyAsync(Wh + (size_t)21 * 4096, Wr, (size_t)84 * 4096 * 4, hipMemcpyDeviceToDevice, stream);

  // 1) ROI pool -> bf16 activations [256, 25088]
  roi_pool_kernel<<<dim3(NROIS, 4), 128, 0, stream>>>(feat, boxes, pooled);

  // 2) FC1: [256,25088] x [4096,25088]^T, tile 256x32, splitK=16 (kps=1568)
  gemm_m256<false><<<dim3(128, 16), 256, 0, stream>>>(pooled, W1, part, H1, D1, 1568, H1);
  reduce_bias_relu<<<1024, 256, 0, stream>>>(part, b1, x1, NROIS * H1, H1 - 1, 16);

  // 3) FC2: [256,4096] x [4096,4096]^T, splitK=8 (kps=512)
  gemm_m256<false><<<dim3(128, 8), 256, 0, stream>>>(x1, W2, part, H1, H1, 512, H1);
  reduce_bias_relu<<<1024, 256, 0, stream>>>(part, b2, x2, NROIS * H1, H1 - 1, 8);

  // 4) heads: [256,4096] x [105,4096]^T (N padded to 128), splitK=16 (kps=256)
  gemm_m256<true><<<dim3(4, 16), 256, 0, stream>>>(x2, Wh, hpart, 128, H1, 256, NHEAD);
  heads_reduce<<<NROIS, 128, 0, stream>>>(hpart, bc, br, out, 16);
}